// Round 1
// baseline (762.679 us; speedup 1.0000x reference)
//
#include <hip/hip_runtime.h>
#include <stdint.h>

#define N_TOK 32768
#define TD 512
#define GE 160
#define WSTRIDE (GE * GE)   // 25600

// ws layout: [0..4) u32 counter | [256..256+4*N_TOK) u32 meta | then float opv[N_TOK]
// meta: bits0-14 token, 15-18 a_lo, 19-22 a_hi, 23-26 b_lo, 27-30 b_hi

__device__ __forceinline__ uint32_t nib_first(uint64_t m, int field) {
    uint32_t bits = (uint32_t)((m >> (field * 16)) & 0xFFFFull);
    return bits ? (uint32_t)__builtin_ctz(bits) : 0u;
}

__global__ __launch_bounds__(256) void prep_kernel(
        const float* __restrict__ x, float* __restrict__ out,
        uint32_t* __restrict__ cnt, uint32_t* __restrict__ meta,
        float* __restrict__ opv, int do_compact) {
    int gwave = (int)((blockIdx.x * 256u + threadIdx.x) >> 6);
    int lane  = (int)(threadIdx.x & 63u);
    if (gwave >= N_TOK) return;
    size_t base = (size_t)gwave * TD;
    // 2 KB copy per token, 64 lanes x 2 float4
    const float4* s4 = (const float4*)(x + base);
    float4* d4 = (float4*)(out + base);
    d4[lane]      = s4[lane];
    d4[lane + 64] = s4[lane + 64];
    // nibble fields are the 64 contiguous floats [64..128): one per lane
    float nv = x[base + 64 + lane];
    uint64_t m = __ballot(nv > 0.5f);
    if (lane == 0 && do_compact) {
        float g0 = x[base + 0];
        float g1 = x[base + 1];
        if (g0 >= 0.5f && g1 >= 0.5f) {
            uint32_t a_lo = nib_first(m, 0);
            uint32_t a_hi = nib_first(m, 1);
            uint32_t b_lo = nib_first(m, 2);
            uint32_t b_hi = nib_first(m, 3);
            uint32_t idx = atomicAdd(cnt, 1u);
            meta[idx] = (uint32_t)gwave | (a_lo << 15) | (a_hi << 19) |
                        (b_lo << 23) | (b_hi << 27);
            opv[idx] = x[base + 29];   // OPCODE_BASE + 27
        }
    }
}

// Block = 256 threads (4 waves) processes 32 tokens = 64 position-vectors.
// LDS h[k][m]: k-major, lane=position -> conflict-free (consecutive lanes,
// consecutive banks). Wave w owns outputs n in [40w, 40w+40): n is
// wave-uniform so W/b reads become scalar broadcast loads.
template <bool COMPACT>
__global__ __launch_bounds__(256) void mlp_kernel(
        const float* __restrict__ x, const float* __restrict__ W,
        const float* __restrict__ b, float* __restrict__ out,
        const uint32_t* __restrict__ cnt, const uint32_t* __restrict__ meta,
        const float* __restrict__ opv) {
    __shared__ float h[GE][64];   // 40 KB
    const int lane = (int)(threadIdx.x & 63u);
    const int wv   = __builtin_amdgcn_readfirstlane((int)(threadIdx.x >> 6));
    const int p    = lane & 1;    // position within token (lo/hi)
    const uint32_t count   = COMPACT ? *cnt : (uint32_t)N_TOK;
    const uint32_t nchunks = (count + 31u) >> 5;

    for (uint32_t ch = blockIdx.x; ch < nchunks; ch += gridDim.x) {
        uint32_t slot = ch * 32u + (uint32_t)(lane >> 1);
        bool active = slot < count;
        int tok = 0;
        float na = 0.f, nb = 0.f, op = 0.f;
        if (COMPACT) {
            if (active) {
                uint32_t mt = meta[slot];
                tok = (int)(mt & 0x7FFFu);
                uint32_t nib = mt >> 15;
                na = (float)((nib >> (p * 4)) & 0xFu);
                nb = (float)((nib >> (8 + p * 4)) & 0xFu);
                op = opv[slot];
            }
        } else {
            tok = (int)slot;
            if (active) {
                size_t tb = (size_t)tok * TD;
                float g0 = x[tb], g1 = x[tb + 1];
                active = (g0 >= 0.5f) && (g1 >= 0.5f);
                if (active) {
                    const float* ap = x + tb + 64 + 16 * p;
                    const float* bp = x + tb + 96 + 16 * p;
                    #pragma unroll
                    for (int i = 15; i >= 0; --i) { if (ap[i] > 0.5f) na = (float)i; }
                    #pragma unroll
                    for (int i = 15; i >= 0; --i) { if (bp[i] > 0.5f) nb = (float)i; }
                    op = x[tb + 29];
                }
            }
        }

        // ---- layer 0: inputs have only 3 nonzeros (features 0, 1, 30) ----
        float c[40];
        {
            const float* W0 = W;
            #pragma unroll
            for (int j = 0; j < 40; ++j) {
                int n = 40 * wv + j;
                float cc = b[n];
                cc = fmaf(W0[n * GE + 0],  na, cc);
                cc = fmaf(W0[n * GE + 1],  nb, cc);
                cc = fmaf(W0[n * GE + 30], op, cc);
                c[j] = fmaxf(cc, 0.f);
            }
        }
        __syncthreads();   // previous chunk's layer-6 readers done
        #pragma unroll
        for (int j = 0; j < 40; ++j) h[40 * wv + j][lane] = c[j];
        __syncthreads();

        // ---- layers 1..5: full 160x160 + ReLU ----
        for (int l = 1; l < 6; ++l) {
            const float* Wl = W + l * WSTRIDE;
            const float* bl = b + l * GE;
            #pragma unroll
            for (int j = 0; j < 40; ++j) c[j] = bl[40 * wv + j];
            for (int k0 = 0; k0 < GE; k0 += 16) {
                float hr[16];
                #pragma unroll
                for (int kk = 0; kk < 16; ++kk) hr[kk] = h[k0 + kk][lane];
                #pragma unroll
                for (int j = 0; j < 40; ++j) {
                    const float* wr = Wl + (40 * wv + j) * GE + k0;
                    #pragma unroll
                    for (int kk = 0; kk < 16; ++kk)
                        c[j] = fmaf(hr[kk], wr[kk], c[j]);
                }
            }
            __syncthreads();
            #pragma unroll
            for (int j = 0; j < 40; ++j)
                h[40 * wv + j][lane] = fmaxf(c[j], 0.f);
            __syncthreads();
        }

        // ---- layer 6: only output index RESULT=2 is ever read ----
        if (wv == 0) {
            const float* W6 = W + 6 * WSTRIDE + 2 * GE;
            float acc = b[6 * GE + 2];
            #pragma unroll 16
            for (int k = 0; k < GE; ++k) acc = fmaf(h[k][lane], W6[k], acc);
            if (active) {
                float r = rintf(acc);                 // half-to-even == jnp.round
                r = fminf(fmaxf(r, 0.f), 15.f);
                int res = (int)r;
                // unique (token, parity) per lane -> plain RMW is race-free
                out[(size_t)tok * TD + 128 + 16 * p + res] += 2.0f;
            }
        }
    }
}

extern "C" void kernel_launch(void* const* d_in, const int* in_sizes, int n_in,
                              void* d_out, int out_size, void* d_ws, size_t ws_size,
                              hipStream_t stream) {
    const float* x = (const float*)d_in[0];
    const float* W = (const float*)d_in[1];
    const float* b = (const float*)d_in[2];
    float* out = (float*)d_out;

    uint32_t* cnt  = (uint32_t*)d_ws;
    uint32_t* meta = (uint32_t*)((char*)d_ws + 256);
    float*    opv  = (float*)((char*)d_ws + 256 + 4 * (size_t)N_TOK);
    bool compact = ws_size >= (size_t)(256 + 8 * (size_t)N_TOK);

    if (compact) hipMemsetAsync(d_ws, 0, 4, stream);   // zero the counter
    prep_kernel<<<N_TOK / 4, 256, 0, stream>>>(x, out, cnt, meta, opv,
                                               compact ? 1 : 0);
    if (compact)
        mlp_kernel<true><<<512, 256, 0, stream>>>(x, W, b, out, cnt, meta, opv);
    else
        mlp_kernel<false><<<512, 256, 0, stream>>>(x, W, b, out, cnt, meta, opv);
}

// Round 2
// 284.938 us; speedup vs baseline: 2.6767x; 2.6767x over previous
//
#include <hip/hip_runtime.h>
#include <stdint.h>

#define N_TOK 32768
#define TD 512
#define GE 160
#define WSTRIDE (GE * GE)   // 25600

// ws layout: [0..4) u32 counter | [256..256+4*N_TOK) u32 meta | then float opv[N_TOK]
// meta: bits0-14 token, 15-18 a_lo, 19-22 a_hi, 23-26 b_lo, 27-30 b_hi

__device__ __forceinline__ uint32_t nib_first(uint64_t m, int field) {
    uint32_t bits = (uint32_t)((m >> (field * 16)) & 0xFFFFull);
    return bits ? (uint32_t)__builtin_ctz(bits) : 0u;
}

// 1024 blocks x 256 threads; each block: copy 32 tokens (4096 float4) flat,
// then wave-per-token ballot decode, per-block LDS compaction, ONE global
// atomic per block (1024 total vs 8192 single-address atomics before).
__global__ __launch_bounds__(256) void prep_kernel(
        const float* __restrict__ x, float* __restrict__ out,
        uint32_t* __restrict__ cnt, uint32_t* __restrict__ meta,
        float* __restrict__ opv, int do_compact) {
    __shared__ uint32_t l_meta[64];
    __shared__ float    l_opv[64];
    __shared__ uint32_t l_cnt, l_base;
    const int tid = (int)threadIdx.x;
    if (tid == 0) l_cnt = 0;

    // flat copy: 32 tokens = 4096 float4, 16 per thread
    size_t blk = (size_t)blockIdx.x * 4096;
    const float4* s4 = ((const float4*)x) + blk;
    float4*       d4 = ((float4*)out) + blk;
    #pragma unroll
    for (int i = 0; i < 16; ++i) d4[tid + 256 * i] = s4[tid + 256 * i];

    if (!do_compact) return;
    __syncthreads();

    const int lane = tid & 63;
    const int wv   = tid >> 6;
    for (int it = 0; it < 8; ++it) {
        int tok = (int)blockIdx.x * 32 + it * 4 + wv;
        size_t base = (size_t)tok * TD;
        float nv = x[base + 64 + lane];           // L1/L2-hot (just copied)
        uint64_t m = __ballot(nv > 0.5f);
        if (lane == 0) {
            float g0 = x[base], g1 = x[base + 1];
            if (g0 >= 0.5f && g1 >= 0.5f) {
                uint32_t idx = atomicAdd(&l_cnt, 1u);
                l_meta[idx] = (uint32_t)tok | (nib_first(m, 0) << 15) |
                              (nib_first(m, 1) << 19) | (nib_first(m, 2) << 23) |
                              (nib_first(m, 3) << 27);
                l_opv[idx] = x[base + 29];        // OPCODE_BASE + 27
            }
        }
    }
    __syncthreads();
    if (tid == 0) l_base = atomicAdd(cnt, l_cnt);
    __syncthreads();
    uint32_t c = l_cnt;
    if ((uint32_t)tid < c) {
        meta[l_base + tid] = l_meta[tid];
        opv[l_base + tid]  = l_opv[tid];
    }
}

// Block = 1024 threads (16 waves) processes 32 tokens = 64 position-vectors.
// Wave wv owns outputs n in [10*wv, 10*wv+10): wave-uniform n -> W/b reads are
// scalar broadcast loads. LDS h[k][pos] k-major: lane=pos, consecutive lanes
// consecutive banks, 2-way (free) aliasing only.
// 16 waves/block, ~256 working blocks -> 4 waves/SIMD (vs 1 before).
template <bool COMPACT>
__global__ __launch_bounds__(1024) void mlp_kernel(
        const float* __restrict__ x, const float* __restrict__ W,
        const float* __restrict__ b, float* __restrict__ out,
        const uint32_t* __restrict__ cnt, const uint32_t* __restrict__ meta,
        const float* __restrict__ opv) {
    __shared__ float h[GE][64];   // 40 KB
    const int lane = (int)(threadIdx.x & 63u);
    const int wv   = __builtin_amdgcn_readfirstlane((int)(threadIdx.x >> 6)); // 0..15
    const int p    = lane & 1;    // position within token (lo/hi)
    const uint32_t count   = COMPACT ? *cnt : (uint32_t)N_TOK;
    const uint32_t nchunks = (count + 31u) >> 5;

    for (uint32_t ch = blockIdx.x; ch < nchunks; ch += gridDim.x) {
        uint32_t slot = ch * 32u + (uint32_t)(lane >> 1);
        bool active = slot < count;
        int tok = 0;
        float na = 0.f, nb = 0.f, op = 0.f;
        if (COMPACT) {
            if (active) {
                uint32_t mt = meta[slot];
                tok = (int)(mt & 0x7FFFu);
                uint32_t nib = mt >> 15;
                na = (float)((nib >> (p * 4)) & 0xFu);
                nb = (float)((nib >> (8 + p * 4)) & 0xFu);
                op = opv[slot];
            }
        } else {
            tok = (int)slot;
            if (active) {
                size_t tb = (size_t)tok * TD;
                float g0 = x[tb], g1 = x[tb + 1];
                active = (g0 >= 0.5f) && (g1 >= 0.5f);
                if (active) {
                    const float* ap = x + tb + 64 + 16 * p;
                    const float* bp = x + tb + 96 + 16 * p;
                    #pragma unroll
                    for (int i = 15; i >= 0; --i) { if (ap[i] > 0.5f) na = (float)i; }
                    #pragma unroll
                    for (int i = 15; i >= 0; --i) { if (bp[i] > 0.5f) nb = (float)i; }
                    op = x[tb + 29];
                }
            }
        }

        // ---- layer 0: inputs have only 3 nonzeros (features 0, 1, 30) ----
        float c[10];
        {
            const float* W0 = W;
            #pragma unroll
            for (int j = 0; j < 10; ++j) {
                int n = 10 * wv + j;
                float cc = b[n];
                cc = fmaf(W0[n * GE + 0],  na, cc);
                cc = fmaf(W0[n * GE + 1],  nb, cc);
                cc = fmaf(W0[n * GE + 30], op, cc);
                c[j] = fmaxf(cc, 0.f);
            }
        }
        __syncthreads();   // previous chunk's layer-6 readers done
        #pragma unroll
        for (int j = 0; j < 10; ++j) h[10 * wv + j][lane] = c[j];
        __syncthreads();

        // ---- layers 1..5: full 160x160 + ReLU ----
        for (int l = 1; l < 6; ++l) {
            const float* Wl = W + l * WSTRIDE;
            const float* bl = b + l * GE;
            #pragma unroll
            for (int j = 0; j < 10; ++j) c[j] = bl[10 * wv + j];
            for (int k0 = 0; k0 < GE; k0 += 16) {
                float hr[16];
                #pragma unroll
                for (int kk = 0; kk < 16; ++kk) hr[kk] = h[k0 + kk][lane];
                #pragma unroll
                for (int j = 0; j < 10; ++j) {
                    const float* wr = Wl + (10 * wv + j) * GE + k0;
                    #pragma unroll
                    for (int kk = 0; kk < 16; ++kk)
                        c[j] = fmaf(hr[kk], wr[kk], c[j]);
                }
            }
            __syncthreads();
            #pragma unroll
            for (int j = 0; j < 10; ++j)
                h[10 * wv + j][lane] = fmaxf(c[j], 0.f);
            __syncthreads();
        }

        // ---- layer 6: only output index RESULT=2 is ever read ----
        if (wv == 0) {
            const float* W6 = W + 6 * WSTRIDE + 2 * GE;
            float acc = b[6 * GE + 2];
            #pragma unroll 16
            for (int k = 0; k < GE; ++k) acc = fmaf(h[k][lane], W6[k], acc);
            if (active) {
                float r = rintf(acc);                 // half-to-even == jnp.round
                r = fminf(fmaxf(r, 0.f), 15.f);
                int res = (int)r;
                // unique (token, parity) per lane -> plain RMW is race-free
                out[(size_t)tok * TD + 128 + 16 * p + res] += 2.0f;
            }
        }
    }
}

extern "C" void kernel_launch(void* const* d_in, const int* in_sizes, int n_in,
                              void* d_out, int out_size, void* d_ws, size_t ws_size,
                              hipStream_t stream) {
    const float* x = (const float*)d_in[0];
    const float* W = (const float*)d_in[1];
    const float* b = (const float*)d_in[2];
    float* out = (float*)d_out;

    uint32_t* cnt  = (uint32_t*)d_ws;
    uint32_t* meta = (uint32_t*)((char*)d_ws + 256);
    float*    opv  = (float*)((char*)d_ws + 256 + 4 * (size_t)N_TOK);
    bool compact = ws_size >= (size_t)(256 + 8 * (size_t)N_TOK);

    if (compact) hipMemsetAsync(d_ws, 0, 4, stream);   // zero the counter
    prep_kernel<<<N_TOK / 32, 256, 0, stream>>>(x, out, cnt, meta, opv,
                                                compact ? 1 : 0);
    if (compact)
        mlp_kernel<true><<<512, 1024, 0, stream>>>(x, W, b, out, cnt, meta, opv);
    else
        mlp_kernel<false><<<512, 1024, 0, stream>>>(x, W, b, out, cnt, meta, opv);
}

// Round 3
// 226.310 us; speedup vs baseline: 3.3701x; 1.2591x over previous
//
#include <hip/hip_runtime.h>
#include <stdint.h>

#define N_TOK 32768
#define TD 512
#define GE 160
#define WSTRIDE (GE * GE)          // 25600
#define WELEMS (7 * WSTRIDE)       // 179200
#define N_MLP_BLK 256
#define N_COPY_BLK 1024

typedef __attribute__((ext_vector_type(8))) short short8;   // 8 bf16 (4 VGPRs)
typedef __attribute__((ext_vector_type(4))) float f32x4;    // MFMA C/D

// ---- ws layout (byte offsets) ----
#define OFF_CNT   0
#define OFF_META  256
#define OFF_OPV   (OFF_META + 4 * N_TOK)     // 131328
#define OFF_RESV  (OFF_OPV + 4 * N_TOK)      // 262400
#define OFF_W1    393728                     // 16B aligned
#define OFF_W2    (OFF_W1 + 2 * WELEMS)      // +358400
#define OFF_W3    (OFF_W2 + 2 * WELEMS)
#define WS_REQ    (OFF_W3 + 2 * WELEMS)      // 1468928

__device__ __forceinline__ uint32_t nib_first(uint64_t m, int field) {
    uint32_t bits = (uint32_t)((m >> (field * 16)) & 0xFFFFull);
    return bits ? (uint32_t)__builtin_ctz(bits) : 0u;
}
__device__ __forceinline__ unsigned short bf16_rne(float f) {
    uint32_t u = __builtin_bit_cast(uint32_t, f);
    return (unsigned short)((u + 0x7FFFu + ((u >> 16) & 1u)) >> 16);
}
__device__ __forceinline__ float bf16_f(unsigned short h) {
    uint32_t u = ((uint32_t)h) << 16;
    return __builtin_bit_cast(float, u);
}

// ============ kernel 1: compact active tokens + split W into 3 bf16 planes ====
__global__ __launch_bounds__(256) void decode_kernel(
        const float* __restrict__ x, const float* __restrict__ W,
        uint32_t* __restrict__ cnt, uint32_t* __restrict__ meta,
        float* __restrict__ opv, unsigned short* __restrict__ W1,
        unsigned short* __restrict__ W2, unsigned short* __restrict__ W3) {
    __shared__ uint32_t l_meta[64];
    __shared__ float    l_opv[64];
    __shared__ uint32_t l_cnt, l_base;
    const int tid = (int)threadIdx.x;
    if (tid == 0) l_cnt = 0;
    __syncthreads();
    const int lane = tid & 63, wv = tid >> 6;
    for (int it = 0; it < 8; ++it) {
        int tok = (int)blockIdx.x * 32 + it * 4 + wv;
        size_t base = (size_t)tok * TD;
        float nv = x[base + 64 + lane];
        uint64_t m = __ballot(nv > 0.5f);
        if (lane == 0) {
            float g0 = x[base], g1 = x[base + 1];
            if (g0 >= 0.5f && g1 >= 0.5f) {
                uint32_t idx = atomicAdd(&l_cnt, 1u);
                l_meta[idx] = (uint32_t)tok | (nib_first(m, 0) << 15) |
                              (nib_first(m, 1) << 19) | (nib_first(m, 2) << 23) |
                              (nib_first(m, 3) << 27);
                l_opv[idx] = x[base + 29];
            }
        }
    }
    __syncthreads();
    if (tid == 0) l_base = atomicAdd(cnt, l_cnt);
    __syncthreads();
    if ((uint32_t)tid < l_cnt) {
        meta[l_base + tid] = l_meta[tid];
        opv[l_base + tid]  = l_opv[tid];
    }
    // W -> bf16 triple-split (exact to ~2^-27 relative)
    int i = (int)blockIdx.x * 256 + tid;
    if (i < WELEMS) {
        float w = W[i];
        unsigned short w1 = bf16_rne(w);  float r  = w - bf16_f(w1);
        unsigned short w2 = bf16_rne(r);  float r2 = r - bf16_f(w2);
        unsigned short w3 = bf16_rne(r2);
        W1[i] = w1; W2[i] = w2; W3[i] = w3;
    }
}

// ============ kernel 2: fused copy + MFMA MLP ============
// blocks [0, N_MLP_BLK): MLP on compacted tokens, results -> resv
// blocks [N_MLP_BLK, +N_COPY_BLK): x -> out copy (overlaps with MLP)
__global__ __launch_bounds__(256) void fused_kernel(
        const float* __restrict__ x, const float* __restrict__ W,
        const float* __restrict__ b, float* __restrict__ out,
        const uint32_t* __restrict__ cnt, const uint32_t* __restrict__ meta,
        const float* __restrict__ opv, uint32_t* __restrict__ resv,
        const unsigned short* __restrict__ W1,
        const unsigned short* __restrict__ W2,
        const unsigned short* __restrict__ W3) {
    __shared__ float h[GE][64];   // 40 KB
    const int tid = (int)threadIdx.x;

    if (blockIdx.x >= N_MLP_BLK) {
        // ------- copy path: 4096 float4 per block, 16/thread, 8 in flight ----
        size_t base = (size_t)(blockIdx.x - N_MLP_BLK) * 4096;
        const float4* s4 = (const float4*)x + base;
        float4* d4 = (float4*)out + base;
        #pragma unroll
        for (int bt = 0; bt < 2; ++bt) {
            float4 t[8];
            #pragma unroll
            for (int i = 0; i < 8; ++i) t[i] = s4[tid + 256 * (bt * 8 + i)];
            #pragma unroll
            for (int i = 0; i < 8; ++i) d4[tid + 256 * (bt * 8 + i)] = t[i];
        }
        return;
    }

    // ------- MLP path: 4 waves, wave = one 16-pos N-tile, owns all 10 M-tiles
    const int lane = tid & 63;
    const int wv   = __builtin_amdgcn_readfirstlane(tid >> 6);  // 0..3 = nt
    const int q    = lane >> 4;          // quad
    const int li   = lane & 15;
    const int p    = lane & 1;           // lo/hi position within token
    const int mypos = 16 * wv + li;      // this lane's B-column / C-column
    const uint32_t count = *cnt;
    const uint32_t nchunks = (count + 31u) >> 5;   // 32 tokens = 64 pos/chunk

    for (uint32_t ch = blockIdx.x; ch < nchunks; ch += N_MLP_BLK) {
        __syncthreads();   // prior chunk's layer-6 readers done with h
        uint32_t slot = ch * 32u + (uint32_t)(lane >> 1);
        bool act = slot < count;
        int tok = 0; float na = 0.f, nb = 0.f, op = 0.f;
        if (act) {
            uint32_t mt_ = meta[slot];
            tok = (int)(mt_ & 0x7FFFu);
            uint32_t nib = mt_ >> 15;
            na = (float)((nib >> (p * 4)) & 0xFu);
            nb = (float)((nib >> (8 + p * 4)) & 0xFu);
            op = opv[slot];
        }

        // ---- layer 0 (exact fp32): wave wv computes outputs 40wv..+39, lane=pos
        {
            #pragma unroll
            for (int j = 0; j < 40; ++j) {
                int n = 40 * wv + j;
                float c = b[n];
                c = fmaf(W[n * GE + 0],  na, c);
                c = fmaf(W[n * GE + 1],  nb, c);
                c = fmaf(W[n * GE + 30], op, c);
                h[n][lane] = fmaxf(c, 0.f);
            }
        }
        __syncthreads();

        // ---- layers 1..5: bf16x3-split MFMA (error ~2^-27, exact-class) ----
        for (int l = 1; l < 6; ++l) {
            const unsigned short* w1p = W1 + l * WSTRIDE;
            const unsigned short* w2p = W2 + l * WSTRIDE;
            const unsigned short* w3p = W3 + l * WSTRIDE;
            const float* bl = b + l * GE;
            f32x4 acc[10];
            #pragma unroll
            for (int mt = 0; mt < 10; ++mt) acc[mt] = (f32x4){0.f, 0.f, 0.f, 0.f};

            for (int kt = 0; kt < 5; ++kt) {
                const int kb = 32 * kt + 8 * q;
                // B-frag: lane holds h[kb..kb+7][mypos]; split into 3 bf16 terms
                short8 B1, B2, B3;
                #pragma unroll
                for (int j = 0; j < 8; ++j) {
                    float v = h[kb + j][mypos];
                    unsigned short b1 = bf16_rne(v);  float r  = v - bf16_f(b1);
                    unsigned short b2 = bf16_rne(r);  float r2 = r - bf16_f(b2);
                    unsigned short b3 = bf16_rne(r2);
                    B1[j] = (short)b1; B2[j] = (short)b2; B3[j] = (short)b3;
                }
                #pragma unroll
                for (int mt = 0; mt < 10; ++mt) {
                    size_t ao = (size_t)(16 * mt + li) * GE + 32 * kt + 8 * q;
                    short8 A1 = *(const short8*)(w1p + ao);
                    short8 A2 = *(const short8*)(w2p + ao);
                    short8 A3 = *(const short8*)(w3p + ao);
                    acc[mt] = __builtin_amdgcn_mfma_f32_16x16x32_bf16(A1, B1, acc[mt], 0, 0, 0);
                    acc[mt] = __builtin_amdgcn_mfma_f32_16x16x32_bf16(A1, B2, acc[mt], 0, 0, 0);
                    acc[mt] = __builtin_amdgcn_mfma_f32_16x16x32_bf16(A2, B1, acc[mt], 0, 0, 0);
                    acc[mt] = __builtin_amdgcn_mfma_f32_16x16x32_bf16(A2, B2, acc[mt], 0, 0, 0);
                    acc[mt] = __builtin_amdgcn_mfma_f32_16x16x32_bf16(A1, B3, acc[mt], 0, 0, 0);
                    acc[mt] = __builtin_amdgcn_mfma_f32_16x16x32_bf16(A3, B1, acc[mt], 0, 0, 0);
                }
            }
            // epilogue: C/D layout col=li (pos), row=4q+r. Own columns only ->
            // no barrier between layers.
            #pragma unroll
            for (int mt = 0; mt < 10; ++mt) {
                #pragma unroll
                for (int r = 0; r < 4; ++r) {
                    int n = 16 * mt + 4 * q + r;
                    float v = acc[mt][r] + bl[n];
                    h[n][mypos] = fmaxf(v, 0.f);
                }
            }
        }
        __syncthreads();

        // ---- layer 6 (exact fp32): only output index RESULT=2 matters ----
        if (wv == 0) {
            const float* W6 = W + 6 * WSTRIDE + 2 * GE;
            float acc = b[6 * GE + 2];
            #pragma unroll 16
            for (int k = 0; k < GE; ++k) acc = fmaf(h[k][lane], W6[k], acc);
            float r_ = fminf(fmaxf(rintf(acc), 0.f), 15.f);
            int res = (int)r_;
            int other = __shfl_xor(res, 1, 64);   // partner parity's result
            if (act && p == 0)
                resv[slot] = (uint32_t)tok | ((uint32_t)res << 15) |
                             ((uint32_t)other << 19);
        }
    }
}

// ============ kernel 3: apply +2.0 one-hots ============
__global__ __launch_bounds__(256) void scatter_kernel(
        const uint32_t* __restrict__ cnt, const uint32_t* __restrict__ resv,
        float* __restrict__ out) {
    uint32_t count = *cnt;
    for (uint32_t i = blockIdx.x * 256u + threadIdx.x; i < count;
         i += gridDim.x * 256u) {
        uint32_t m = resv[i];
        size_t base = (size_t)(m & 0x7FFFu) * TD;
        out[base + 128 + ((m >> 15) & 0xFu)] += 2.0f;
        out[base + 144 + ((m >> 19) & 0xFu)] += 2.0f;
    }
}

// ============ legacy fallback (round-2 path) if ws is too small ============
__global__ __launch_bounds__(256) void prep_legacy(
        const float* __restrict__ x, float* __restrict__ out,
        uint32_t* __restrict__ cnt, uint32_t* __restrict__ meta,
        float* __restrict__ opv, int do_compact) {
    __shared__ uint32_t l_meta[64];
    __shared__ float    l_opv[64];
    __shared__ uint32_t l_cnt, l_base;
    const int tid = (int)threadIdx.x;
    if (tid == 0) l_cnt = 0;
    size_t blk = (size_t)blockIdx.x * 4096;
    const float4* s4 = ((const float4*)x) + blk;
    float4*       d4 = ((float4*)out) + blk;
    #pragma unroll
    for (int i = 0; i < 16; ++i) d4[tid + 256 * i] = s4[tid + 256 * i];
    if (!do_compact) return;
    __syncthreads();
    const int lane = tid & 63, wv = tid >> 6;
    for (int it = 0; it < 8; ++it) {
        int tok = (int)blockIdx.x * 32 + it * 4 + wv;
        size_t base = (size_t)tok * TD;
        float nv = x[base + 64 + lane];
        uint64_t m = __ballot(nv > 0.5f);
        if (lane == 0) {
            float g0 = x[base], g1 = x[base + 1];
            if (g0 >= 0.5f && g1 >= 0.5f) {
                uint32_t idx = atomicAdd(&l_cnt, 1u);
                l_meta[idx] = (uint32_t)tok | (nib_first(m, 0) << 15) |
                              (nib_first(m, 1) << 19) | (nib_first(m, 2) << 23) |
                              (nib_first(m, 3) << 27);
                l_opv[idx] = x[base + 29];
            }
        }
    }
    __syncthreads();
    if (tid == 0) l_base = atomicAdd(cnt, l_cnt);
    __syncthreads();
    if ((uint32_t)tid < l_cnt) {
        meta[l_base + tid] = l_meta[tid];
        opv[l_base + tid]  = l_opv[tid];
    }
}

template <bool COMPACT>
__global__ __launch_bounds__(1024) void mlp_legacy(
        const float* __restrict__ x, const float* __restrict__ W,
        const float* __restrict__ b, float* __restrict__ out,
        const uint32_t* __restrict__ cnt, const uint32_t* __restrict__ meta,
        const float* __restrict__ opv) {
    __shared__ float h[GE][64];
    const int lane = (int)(threadIdx.x & 63u);
    const int wv   = __builtin_amdgcn_readfirstlane((int)(threadIdx.x >> 6));
    const int p    = lane & 1;
    const uint32_t count   = COMPACT ? *cnt : (uint32_t)N_TOK;
    const uint32_t nchunks = (count + 31u) >> 5;
    for (uint32_t ch = blockIdx.x; ch < nchunks; ch += gridDim.x) {
        uint32_t slot = ch * 32u + (uint32_t)(lane >> 1);
        bool active = slot < count;
        int tok = 0;
        float na = 0.f, nb = 0.f, op = 0.f;
        if (COMPACT) {
            if (active) {
                uint32_t mt = meta[slot];
                tok = (int)(mt & 0x7FFFu);
                uint32_t nib = mt >> 15;
                na = (float)((nib >> (p * 4)) & 0xFu);
                nb = (float)((nib >> (8 + p * 4)) & 0xFu);
                op = opv[slot];
            }
        } else {
            tok = (int)slot;
            if (active) {
                size_t tb = (size_t)tok * TD;
                float g0 = x[tb], g1 = x[tb + 1];
                active = (g0 >= 0.5f) && (g1 >= 0.5f);
                if (active) {
                    const float* ap = x + tb + 64 + 16 * p;
                    const float* bp = x + tb + 96 + 16 * p;
                    #pragma unroll
                    for (int i = 15; i >= 0; --i) { if (ap[i] > 0.5f) na = (float)i; }
                    #pragma unroll
                    for (int i = 15; i >= 0; --i) { if (bp[i] > 0.5f) nb = (float)i; }
                    op = x[tb + 29];
                }
            }
        }
        float c[10];
        {
            #pragma unroll
            for (int j = 0; j < 10; ++j) {
                int n = 10 * wv + j;
                float cc = b[n];
                cc = fmaf(W[n * GE + 0],  na, cc);
                cc = fmaf(W[n * GE + 1],  nb, cc);
                cc = fmaf(W[n * GE + 30], op, cc);
                c[j] = fmaxf(cc, 0.f);
            }
        }
        __syncthreads();
        #pragma unroll
        for (int j = 0; j < 10; ++j) h[10 * wv + j][lane] = c[j];
        __syncthreads();
        for (int l = 1; l < 6; ++l) {
            const float* Wl = W + l * WSTRIDE;
            const float* bl = b + l * GE;
            #pragma unroll
            for (int j = 0; j < 10; ++j) c[j] = bl[10 * wv + j];
            for (int k0 = 0; k0 < GE; k0 += 16) {
                float hr[16];
                #pragma unroll
                for (int kk = 0; kk < 16; ++kk) hr[kk] = h[k0 + kk][lane];
                #pragma unroll
                for (int j = 0; j < 10; ++j) {
                    const float* wr = Wl + (10 * wv + j) * GE + k0;
                    #pragma unroll
                    for (int kk = 0; kk < 16; ++kk)
                        c[j] = fmaf(hr[kk], wr[kk], c[j]);
                }
            }
            __syncthreads();
            #pragma unroll
            for (int j = 0; j < 10; ++j)
                h[10 * wv + j][lane] = fmaxf(c[j], 0.f);
            __syncthreads();
        }
        if (wv == 0) {
            const float* W6 = W + 6 * WSTRIDE + 2 * GE;
            float acc = b[6 * GE + 2];
            #pragma unroll 16
            for (int k = 0; k < GE; ++k) acc = fmaf(h[k][lane], W6[k], acc);
            if (active) {
                float r = rintf(acc);
                r = fminf(fmaxf(r, 0.f), 15.f);
                int res = (int)r;
                out[(size_t)tok * TD + 128 + 16 * p + res] += 2.0f;
            }
        }
    }
}

extern "C" void kernel_launch(void* const* d_in, const int* in_sizes, int n_in,
                              void* d_out, int out_size, void* d_ws, size_t ws_size,
                              hipStream_t stream) {
    const float* x = (const float*)d_in[0];
    const float* W = (const float*)d_in[1];
    const float* b = (const float*)d_in[2];
    float* out = (float*)d_out;

    uint32_t* cnt  = (uint32_t*)((char*)d_ws + OFF_CNT);
    uint32_t* meta = (uint32_t*)((char*)d_ws + OFF_META);
    float*    opv  = (float*)((char*)d_ws + OFF_OPV);
    uint32_t* resv = (uint32_t*)((char*)d_ws + OFF_RESV);
    unsigned short* W1 = (unsigned short*)((char*)d_ws + OFF_W1);
    unsigned short* W2 = (unsigned short*)((char*)d_ws + OFF_W2);
    unsigned short* W3 = (unsigned short*)((char*)d_ws + OFF_W3);

    if (ws_size >= (size_t)WS_REQ) {
        hipMemsetAsync(d_ws, 0, 4, stream);
        decode_kernel<<<1024, 256, 0, stream>>>(x, W, cnt, meta, opv, W1, W2, W3);
        fused_kernel<<<N_MLP_BLK + N_COPY_BLK, 256, 0, stream>>>(
            x, W, b, out, cnt, meta, opv, resv, W1, W2, W3);
        scatter_kernel<<<64, 256, 0, stream>>>(cnt, resv, out);
    } else {
        bool compact = ws_size >= (size_t)(256 + 8 * (size_t)N_TOK);
        if (compact) hipMemsetAsync(d_ws, 0, 4, stream);
        prep_legacy<<<N_TOK / 32, 256, 0, stream>>>(x, out, cnt, meta, opv,
                                                    compact ? 1 : 0);
        if (compact)
            mlp_legacy<true><<<512, 1024, 0, stream>>>(x, W, b, out, cnt, meta, opv);
        else
            mlp_legacy<false><<<512, 1024, 0, stream>>>(x, W, b, out, cnt, meta, opv);
    }
}

// Round 4
// 172.160 us; speedup vs baseline: 4.4301x; 1.3145x over previous
//
#include <hip/hip_runtime.h>
#include <stdint.h>

#define N_TOK 32768
#define TD 512
#define GE 160
#define WSTRIDE (GE * GE)          // 25600
#define N_MLP_BLK 512
#define N_COPY_BLK 1024
#define HSTR 172                   // LDS row stride (ushorts): 4-way max, 8B-aligned

typedef __attribute__((ext_vector_type(8))) short short8;   // 8 bf16
typedef __attribute__((ext_vector_type(4))) float f32x4;    // MFMA C/D
typedef __attribute__((ext_vector_type(4))) unsigned short us4;

// ---- ws layout (byte offsets) ----
#define OFF_CNT   0
#define OFF_META  256
#define OFF_OPV   (OFF_META + 4 * N_TOK)     // 131328
#define OFF_L0C   (OFF_OPV + 4 * N_TOK)      // 262400 (160 float4)
#define OFF_WF    (OFF_L0C + 2560 + 256)     // 265216, 16B aligned
#define WS_REQ    (OFF_WF + 250 * 3072)      // 1033216

__device__ __forceinline__ uint32_t nib_first(uint64_t m, int field) {
    uint32_t bits = (uint32_t)((m >> (field * 16)) & 0xFFFFull);
    return bits ? (uint32_t)__builtin_ctz(bits) : 0u;
}
__device__ __forceinline__ unsigned short bf16_rne(float f) {
    uint32_t u = __builtin_bit_cast(uint32_t, f);
    return (unsigned short)((u + 0x7FFFu + ((u >> 16) & 1u)) >> 16);
}
__device__ __forceinline__ float bf16_f(unsigned short h) {
    uint32_t u = ((uint32_t)h) << 16;
    return __builtin_bit_cast(float, u);
}
__device__ __forceinline__ void split3(float v, unsigned short& s1,
                                       unsigned short& s2, unsigned short& s3) {
    s1 = bf16_rne(v); float r  = v - bf16_f(s1);
    s2 = bf16_rne(r); float r2 = r - bf16_f(s2);
    s3 = bf16_rne(r2);
}

// ===== kernel 1: token compaction + frag-ordered bf16x3 W planes + L0 coeffs ==
__global__ __launch_bounds__(256) void decode_kernel(
        const float* __restrict__ x, const float* __restrict__ W,
        const float* __restrict__ b, uint32_t* __restrict__ cnt,
        uint32_t* __restrict__ meta, float* __restrict__ opv,
        float4* __restrict__ l0c, unsigned short* __restrict__ Wf) {
    const int tid = (int)threadIdx.x;
    if (blockIdx.x < 1024) {
        __shared__ uint32_t l_meta[64];
        __shared__ float    l_opv[64];
        __shared__ uint32_t l_cnt, l_base;
        if (tid == 0) l_cnt = 0;
        __syncthreads();
        const int lane = tid & 63, w = tid >> 6;
        for (int it = 0; it < 8; ++it) {
            int tok = (int)blockIdx.x * 32 + it * 4 + w;
            size_t base = (size_t)tok * TD;
            float nv = x[base + 64 + lane];
            uint64_t m = __ballot(nv > 0.5f);
            if (lane == 0) {
                float g0 = x[base], g1 = x[base + 1];
                if (g0 >= 0.5f && g1 >= 0.5f) {
                    uint32_t idx = atomicAdd(&l_cnt, 1u);
                    l_meta[idx] = (uint32_t)tok | (nib_first(m, 0) << 15) |
                                  (nib_first(m, 1) << 19) | (nib_first(m, 2) << 23) |
                                  (nib_first(m, 3) << 27);
                    l_opv[idx] = x[base + 29];
                }
            }
        }
        __syncthreads();
        if (tid == 0) l_base = atomicAdd(cnt, l_cnt);
        __syncthreads();
        if ((uint32_t)tid < l_cnt) {
            meta[l_base + tid] = l_meta[tid];
            opv[l_base + tid]  = l_opv[tid];
        }
        return;
    }
    // ---- W-fragment reorder: tile (l,kt,mt) -> 3 planes x 64 lanes x 16 B ----
    int wid = ((int)blockIdx.x - 1024) * 256 + tid;
    if (wid < 16000) {
        int tile = wid >> 6, lane = wid & 63;
        int l = 1 + tile / 50, rem = tile % 50, kt = rem / 10, mt = rem % 10;
        int li = lane & 15, q = lane >> 4;
        const float* src = W + (size_t)l * WSTRIDE + (size_t)(16 * mt + li) * GE +
                           32 * kt + 8 * q;
        short8 A1, A2, A3;
        #pragma unroll
        for (int j = 0; j < 8; ++j) {
            unsigned short s1, s2, s3;
            split3(src[j], s1, s2, s3);
            A1[j] = (short)s1; A2[j] = (short)s2; A3[j] = (short)s3;
        }
        unsigned short* tb = Wf + (size_t)tile * 1536 + lane * 8;
        *(short8*)(tb)        = A1;
        *(short8*)(tb + 512)  = A2;
        *(short8*)(tb + 1024) = A3;
    } else if (wid < 16160) {
        int n = wid - 16000;
        l0c[n] = make_float4(W[(size_t)n * GE + 0], W[(size_t)n * GE + 1],
                             W[(size_t)n * GE + 30], b[n]);
    }
}

// ===== kernel 2: fused copy + MFMA MLP (direct one-hot region write) =====
__global__ __launch_bounds__(256, 3) void fused_kernel(
        const float* __restrict__ x, const float* __restrict__ W,
        const float* __restrict__ b, float* __restrict__ out,
        const uint32_t* __restrict__ cnt, const uint32_t* __restrict__ meta,
        const float* __restrict__ opv, const float4* __restrict__ l0c,
        const unsigned short* __restrict__ Wf) {
    __shared__ unsigned short hs[3][32][HSTR];   // 33 KB: bf16x3 h, [pos][k]
    const int tid = (int)threadIdx.x;

    if (blockIdx.x >= N_MLP_BLK) {
        // ---- copy path: 32 tokens/block; skip [128,160) for active tokens ----
        const int lane = tid & 63, w = tid >> 6;
        int t0 = ((int)blockIdx.x - N_MLP_BLK) * 32 + w * 8;
        const float4* s4 = (const float4*)x;
        float4* d4 = (float4*)out;
        bool gate_lane = (lane >= 32 && lane < 40);   // f4 idx 32..39 = [128,160)
        #pragma unroll
        for (int it = 0; it < 8; ++it) {
            int t = t0 + it;
            size_t fb = (size_t)t * 128;
            float4 v0 = s4[fb + lane];
            float4 v1 = s4[fb + 64 + lane];
            bool skip = false;
            if (gate_lane) {
                float g0 = x[(size_t)t * TD], g1 = x[(size_t)t * TD + 1];
                skip = (g0 >= 0.5f) && (g1 >= 0.5f);
            }
            if (!skip) d4[fb + lane] = v0;
            d4[fb + 64 + lane] = v1;
        }
        return;
    }

    // ---- MLP path: 4 waves; wave wv = M-group over mts, both 16-pos N-tiles
    const int lane = tid & 63;
    const int wv   = __builtin_amdgcn_readfirstlane(tid >> 6);   // 0..3
    const int q    = lane >> 4;
    const int li   = lane & 15;
    const int half = lane >> 5, posid = lane & 31;
    const int mstart_tab[4] = {0, 3, 5, 7};
    const int mcnt_tab[4]   = {3, 2, 2, 3};
    const int mystart = mstart_tab[wv], mycnt = mcnt_tab[wv];
    const uint32_t count = *cnt;
    const uint32_t nchunks = (count + 15u) >> 4;   // 16 tokens = 32 pos / chunk

    for (uint32_t ch = blockIdx.x; ch < nchunks; ch += N_MLP_BLK) {
        __syncthreads();   // prior chunk's layer-6 readers done with hs

        // ---- layer 0 (exact fp32, same op order as R3) ----
        {
            uint32_t slot0 = ch * 16u + (uint32_t)(posid >> 1);
            float na = 0.f, nb_ = 0.f, op = 0.f;
            if (slot0 < count) {
                uint32_t m = meta[slot0];
                int p = posid & 1;
                na  = (float)((m >> (15 + p * 4)) & 0xFu);
                nb_ = (float)((m >> (23 + p * 4)) & 0xFu);
                op  = opv[slot0];
            }
            #pragma unroll
            for (int g = 0; g < 5; ++g) {
                int nb4 = 40 * wv + 20 * half + 4 * g;
                us4 p1, p2, p3;
                #pragma unroll
                for (int r = 0; r < 4; ++r) {
                    float4 cc = l0c[nb4 + r];
                    float c = cc.w;
                    c = fmaf(cc.x, na, c);
                    c = fmaf(cc.y, nb_, c);
                    c = fmaf(cc.z, op, c);
                    c = fmaxf(c, 0.f);
                    unsigned short s1, s2, s3;
                    split3(c, s1, s2, s3);
                    p1[r] = s1; p2[r] = s2; p3[r] = s3;
                }
                *(us4*)&hs[0][posid][nb4] = p1;
                *(us4*)&hs[1][posid][nb4] = p2;
                *(us4*)&hs[2][posid][nb4] = p3;
            }
        }
        __syncthreads();

        // ---- layers 1..5: bf16x3 MFMA, coalesced A-frags, zero redundancy ----
        for (int l = 1; l < 6; ++l) {
            const float* bl = b + l * GE;
            f32x4 acc[3][2];
            #pragma unroll
            for (int mi = 0; mi < 3; ++mi)
                #pragma unroll
                for (int nt = 0; nt < 2; ++nt)
                    acc[mi][nt] = (f32x4){0.f, 0.f, 0.f, 0.f};

            for (int kt = 0; kt < 5; ++kt) {
                const int k0 = 32 * kt + 8 * q;
                short8 B1[2], B2[2], B3[2];
                #pragma unroll
                for (int nt = 0; nt < 2; ++nt) {
                    int pos = 16 * nt + li;
                    us4 lo1 = *(const us4*)&hs[0][pos][k0];
                    us4 hi1 = *(const us4*)&hs[0][pos][k0 + 4];
                    us4 lo2 = *(const us4*)&hs[1][pos][k0];
                    us4 hi2 = *(const us4*)&hs[1][pos][k0 + 4];
                    us4 lo3 = *(const us4*)&hs[2][pos][k0];
                    us4 hi3 = *(const us4*)&hs[2][pos][k0 + 4];
                    #pragma unroll
                    for (int j = 0; j < 4; ++j) {
                        B1[nt][j] = (short)lo1[j]; B1[nt][4 + j] = (short)hi1[j];
                        B2[nt][j] = (short)lo2[j]; B2[nt][4 + j] = (short)hi2[j];
                        B3[nt][j] = (short)lo3[j]; B3[nt][4 + j] = (short)hi3[j];
                    }
                }
                #pragma unroll
                for (int mi = 0; mi < 3; ++mi) {
                    if (mi < mycnt) {
                        int mt = mystart + mi;
                        int tidx = ((l - 1) * 5 + kt) * 10 + mt;
                        const unsigned short* tb = Wf + (size_t)tidx * 1536 + lane * 8;
                        short8 A1 = *(const short8*)(tb);
                        short8 A2 = *(const short8*)(tb + 512);
                        short8 A3 = *(const short8*)(tb + 1024);
                        #pragma unroll
                        for (int nt = 0; nt < 2; ++nt) {
                            f32x4 a = acc[mi][nt];
                            a = __builtin_amdgcn_mfma_f32_16x16x32_bf16(A1, B1[nt], a, 0, 0, 0);
                            a = __builtin_amdgcn_mfma_f32_16x16x32_bf16(A1, B2[nt], a, 0, 0, 0);
                            a = __builtin_amdgcn_mfma_f32_16x16x32_bf16(A2, B1[nt], a, 0, 0, 0);
                            a = __builtin_amdgcn_mfma_f32_16x16x32_bf16(A2, B2[nt], a, 0, 0, 0);
                            a = __builtin_amdgcn_mfma_f32_16x16x32_bf16(A1, B3[nt], a, 0, 0, 0);
                            a = __builtin_amdgcn_mfma_f32_16x16x32_bf16(A3, B1[nt], a, 0, 0, 0);
                            acc[mi][nt] = a;
                        }
                    }
                }
            }
            __syncthreads();   // all reads of layer l-1 done before overwrite
            #pragma unroll
            for (int mi = 0; mi < 3; ++mi) {
                if (mi < mycnt) {
                    int nb4 = 16 * (mystart + mi) + 4 * q;
                    #pragma unroll
                    for (int nt = 0; nt < 2; ++nt) {
                        int pos = 16 * nt + li;
                        us4 p1, p2, p3;
                        #pragma unroll
                        for (int r = 0; r < 4; ++r) {
                            float v = fmaxf(acc[mi][nt][r] + bl[nb4 + r], 0.f);
                            unsigned short s1, s2, s3;
                            split3(v, s1, s2, s3);
                            p1[r] = s1; p2[r] = s2; p3[r] = s3;
                        }
                        *(us4*)&hs[0][pos][nb4] = p1;
                        *(us4*)&hs[1][pos][nb4] = p2;
                        *(us4*)&hs[2][pos][nb4] = p3;
                    }
                }
            }
            __syncthreads();
        }

        // ---- layer 6 (row 2 only) + direct [128,160) region write ----
        if (wv == 0) {
            const float* W6 = W + 6 * WSTRIDE + 2 * GE;
            float accp = (half == 0) ? b[6 * GE + 2] : 0.f;
            #pragma unroll
            for (int kb = 0; kb < 10; ++kb) {
                int k0 = 80 * half + 8 * kb;
                us4 a0 = *(const us4*)&hs[0][posid][k0];
                us4 a1 = *(const us4*)&hs[0][posid][k0 + 4];
                us4 b0 = *(const us4*)&hs[1][posid][k0];
                us4 b1 = *(const us4*)&hs[1][posid][k0 + 4];
                us4 c0 = *(const us4*)&hs[2][posid][k0];
                us4 c1 = *(const us4*)&hs[2][posid][k0 + 4];
                const float4* w6f = (const float4*)(W6 + k0);
                float4 w0 = w6f[0], w1 = w6f[1];
                const float* wp0 = (const float*)&w0;
                const float* wp1 = (const float*)&w1;
                #pragma unroll
                for (int j = 0; j < 4; ++j) {
                    float v = (bf16_f(a0[j]) + bf16_f(b0[j])) + bf16_f(c0[j]);
                    accp = fmaf(v, wp0[j], accp);
                }
                #pragma unroll
                for (int j = 0; j < 4; ++j) {
                    float v = (bf16_f(a1[j]) + bf16_f(b1[j])) + bf16_f(c1[j]);
                    accp = fmaf(v, wp1[j], accp);
                }
            }
            float full = accp + __shfl_down(accp, 32);
            int res = (int)fminf(fmaxf(rintf(full), 0.f), 15.f);
            int rhi = __shfl_down(res, 1);
            if (lane < 32 && !(lane & 1)) {
                uint32_t slot = ch * 16u + (uint32_t)(lane >> 1);
                if (slot < count) {
                    int tok = (int)(meta[slot] & 0x7FFFu);
                    const float4* xf = (const float4*)(x + (size_t)tok * TD + 128);
                    float4* of = (float4*)(out + (size_t)tok * TD + 128);
                    int rl = res, rh = 16 + rhi;
                    #pragma unroll
                    for (int i = 0; i < 8; ++i) {
                        float4 v = xf[i];
                        int e = 4 * i;
                        v.x += ((e == rl) || (e == rh)) ? 2.f : 0.f;
                        v.y += ((e + 1 == rl) || (e + 1 == rh)) ? 2.f : 0.f;
                        v.z += ((e + 2 == rl) || (e + 2 == rh)) ? 2.f : 0.f;
                        v.w += ((e + 3 == rl) || (e + 3 == rh)) ? 2.f : 0.f;
                        of[i] = v;
                    }
                }
            }
        }
    }
}

// ============ legacy fallback (R2 path, exact fp32) ============
__global__ __launch_bounds__(256) void prep_legacy(
        const float* __restrict__ x, float* __restrict__ out,
        uint32_t* __restrict__ cnt, uint32_t* __restrict__ meta,
        float* __restrict__ opv, int do_compact) {
    __shared__ uint32_t l_meta[64];
    __shared__ float    l_opv[64];
    __shared__ uint32_t l_cnt, l_base;
    const int tid = (int)threadIdx.x;
    if (tid == 0) l_cnt = 0;
    size_t blk = (size_t)blockIdx.x * 4096;
    const float4* s4 = ((const float4*)x) + blk;
    float4*       d4 = ((float4*)out) + blk;
    #pragma unroll
    for (int i = 0; i < 16; ++i) d4[tid + 256 * i] = s4[tid + 256 * i];
    if (!do_compact) return;
    __syncthreads();
    const int lane = tid & 63, w = tid >> 6;
    for (int it = 0; it < 8; ++it) {
        int tok = (int)blockIdx.x * 32 + it * 4 + w;
        size_t base = (size_t)tok * TD;
        float nv = x[base + 64 + lane];
        uint64_t m = __ballot(nv > 0.5f);
        if (lane == 0) {
            float g0 = x[base], g1 = x[base + 1];
            if (g0 >= 0.5f && g1 >= 0.5f) {
                uint32_t idx = atomicAdd(&l_cnt, 1u);
                l_meta[idx] = (uint32_t)tok | (nib_first(m, 0) << 15) |
                              (nib_first(m, 1) << 19) | (nib_first(m, 2) << 23) |
                              (nib_first(m, 3) << 27);
                l_opv[idx] = x[base + 29];
            }
        }
    }
    __syncthreads();
    if (tid == 0) l_base = atomicAdd(cnt, l_cnt);
    __syncthreads();
    if ((uint32_t)tid < l_cnt) {
        meta[l_base + tid] = l_meta[tid];
        opv[l_base + tid]  = l_opv[tid];
    }
}

template <bool COMPACT>
__global__ __launch_bounds__(1024) void mlp_legacy(
        const float* __restrict__ x, const float* __restrict__ W,
        const float* __restrict__ b, float* __restrict__ out,
        const uint32_t* __restrict__ cnt, const uint32_t* __restrict__ meta,
        const float* __restrict__ opv) {
    __shared__ float h[GE][64];
    const int lane = (int)(threadIdx.x & 63u);
    const int w    = __builtin_amdgcn_readfirstlane((int)(threadIdx.x >> 6));
    const int p    = lane & 1;
    const uint32_t count   = COMPACT ? *cnt : (uint32_t)N_TOK;
    const uint32_t nchunks = (count + 31u) >> 5;
    for (uint32_t ch = blockIdx.x; ch < nchunks; ch += gridDim.x) {
        uint32_t slot = ch * 32u + (uint32_t)(lane >> 1);
        bool active = slot < count;
        int tok = 0;
        float na = 0.f, nb = 0.f, op = 0.f;
        if (COMPACT) {
            if (active) {
                uint32_t mt = meta[slot];
                tok = (int)(mt & 0x7FFFu);
                uint32_t nib = mt >> 15;
                na = (float)((nib >> (p * 4)) & 0xFu);
                nb = (float)((nib >> (8 + p * 4)) & 0xFu);
                op = opv[slot];
            }
        } else {
            tok = (int)slot;
            if (active) {
                size_t tb = (size_t)tok * TD;
                float g0 = x[tb], g1 = x[tb + 1];
                active = (g0 >= 0.5f) && (g1 >= 0.5f);
                if (active) {
                    const float* ap = x + tb + 64 + 16 * p;
                    const float* bp = x + tb + 96 + 16 * p;
                    #pragma unroll
                    for (int i = 15; i >= 0; --i) { if (ap[i] > 0.5f) na = (float)i; }
                    #pragma unroll
                    for (int i = 15; i >= 0; --i) { if (bp[i] > 0.5f) nb = (float)i; }
                    op = x[tb + 29];
                }
            }
        }
        float c[10];
        {
            #pragma unroll
            for (int j = 0; j < 10; ++j) {
                int n = 10 * w + j;
                float cc = b[n];
                cc = fmaf(W[n * GE + 0],  na, cc);
                cc = fmaf(W[n * GE + 1],  nb, cc);
                cc = fmaf(W[n * GE + 30], op, cc);
                c[j] = fmaxf(cc, 0.f);
            }
        }
        __syncthreads();
        #pragma unroll
        for (int j = 0; j < 10; ++j) h[10 * w + j][lane] = c[j];
        __syncthreads();
        for (int l = 1; l < 6; ++l) {
            const float* Wl = W + l * WSTRIDE;
            const float* bl = b + l * GE;
            #pragma unroll
            for (int j = 0; j < 10; ++j) c[j] = bl[10 * w + j];
            for (int k0 = 0; k0 < GE; k0 += 16) {
                float hr[16];
                #pragma unroll
                for (int kk = 0; kk < 16; ++kk) hr[kk] = h[k0 + kk][lane];
                #pragma unroll
                for (int j = 0; j < 10; ++j) {
                    const float* wr = Wl + (10 * w + j) * GE + k0;
                    #pragma unroll
                    for (int kk = 0; kk < 16; ++kk)
                        c[j] = fmaf(hr[kk], wr[kk], c[j]);
                }
            }
            __syncthreads();
            #pragma unroll
            for (int j = 0; j < 10; ++j)
                h[10 * w + j][lane] = fmaxf(c[j], 0.f);
            __syncthreads();
        }
        if (w == 0) {
            const float* W6 = W + 6 * WSTRIDE + 2 * GE;
            float acc = b[6 * GE + 2];
            #pragma unroll 16
            for (int k = 0; k < GE; ++k) acc = fmaf(h[k][lane], W6[k], acc);
            if (active) {
                float r = rintf(acc);
                r = fminf(fmaxf(r, 0.f), 15.f);
                int res = (int)r;
                out[(size_t)tok * TD + 128 + 16 * p + res] += 2.0f;
            }
        }
    }
}

extern "C" void kernel_launch(void* const* d_in, const int* in_sizes, int n_in,
                              void* d_out, int out_size, void* d_ws, size_t ws_size,
                              hipStream_t stream) {
    const float* x = (const float*)d_in[0];
    const float* W = (const float*)d_in[1];
    const float* b = (const float*)d_in[2];
    float* out = (float*)d_out;

    uint32_t* cnt  = (uint32_t*)((char*)d_ws + OFF_CNT);
    uint32_t* meta = (uint32_t*)((char*)d_ws + OFF_META);
    float*    opv  = (float*)((char*)d_ws + OFF_OPV);
    float4*   l0c  = (float4*)((char*)d_ws + OFF_L0C);
    unsigned short* Wf = (unsigned short*)((char*)d_ws + OFF_WF);

    if (ws_size >= (size_t)WS_REQ) {
        hipMemsetAsync(d_ws, 0, 4, stream);
        decode_kernel<<<1024 + 64, 256, 0, stream>>>(x, W, b, cnt, meta, opv,
                                                     l0c, Wf);
        fused_kernel<<<N_MLP_BLK + N_COPY_BLK, 256, 0, stream>>>(
            x, W, b, out, cnt, meta, opv, l0c, Wf);
    } else {
        bool compact = ws_size >= (size_t)(256 + 8 * (size_t)N_TOK);
        if (compact) hipMemsetAsync(d_ws, 0, 4, stream);
        prep_legacy<<<N_TOK / 32, 256, 0, stream>>>(x, out, cnt, meta, opv,
                                                    compact ? 1 : 0);
        if (compact)
            mlp_legacy<true><<<512, 1024, 0, stream>>>(x, W, b, out, cnt, meta, opv);
        else
            mlp_legacy<false><<<512, 1024, 0, stream>>>(x, W, b, out, cnt, meta, opv);
    }
}